// Round 4
// baseline (261.756 us; speedup 1.0000x reference)
//
#include <hip/hip_runtime.h>

#define N_NODES 8192
#define N_EDGES 262144
#define NFEAT 200
#define NHID 128

// ---------------- GEMM: C[nrows,128] = A[nrows,K] @ W[128,K]^T ----------------
template<int K>
__global__ __launch_bounds__(128) void gemm_rows(const float* __restrict__ A,
                                                 const float* __restrict__ W,
                                                 float* __restrict__ C,
                                                 int nrows) {
    __shared__ float a_s[8 * K];
    int row0 = blockIdx.x * 8;
    const float* Ab = A + (size_t)row0 * K;
    for (int idx = threadIdx.x; idx < 8 * K; idx += 128) a_s[idx] = Ab[idx];
    __syncthreads();
    int j = threadIdx.x;
    float acc[8] = {0.f, 0.f, 0.f, 0.f, 0.f, 0.f, 0.f, 0.f};
    const float4* W4 = (const float4*)(W + (size_t)j * K);
    for (int k4 = 0; k4 < K / 4; ++k4) {
        float4 w = W4[k4];
        int k = k4 * 4;
        #pragma unroll
        for (int r = 0; r < 8; ++r) {
            const float* ar = a_s + r * K + k;
            acc[r] += ar[0] * w.x + ar[1] * w.y + ar[2] * w.z + ar[3] * w.w;
        }
    }
    #pragma unroll
    for (int r = 0; r < 8; ++r) C[(size_t)(row0 + r) * 128 + j] = acc[r];
}

// ---------------- CSR build: histogram of dst ----------------
__global__ __launch_bounds__(256) void hist_kernel(const int* __restrict__ ei,
                                                   int* __restrict__ deg, int E) {
    const int* dst = ei + E;
    for (int e = blockIdx.x * blockDim.x + threadIdx.x; e < E; e += gridDim.x * blockDim.x)
        atomicAdd(&deg[dst[e]], 1);
}

// single block, 256 threads: exclusive prefix sum of deg[8192] -> row_start, cursor
__global__ __launch_bounds__(256) void scan_kernel(const int* __restrict__ deg,
                                                   int* __restrict__ row_start,
                                                   int* __restrict__ cursor) {
    __shared__ int part[256];
    __shared__ int partx[257];
    int tid = threadIdx.x;
    int base = tid * 32;
    int s = 0;
    for (int i = 0; i < 32; ++i) s += deg[base + i];
    part[tid] = s;
    __syncthreads();
    if (tid == 0) {
        int run = 0;
        for (int i = 0; i < 256; ++i) { partx[i] = run; run += part[i]; }
        partx[256] = run;
    }
    __syncthreads();
    int run = partx[tid];
    for (int i = 0; i < 32; ++i) {
        row_start[base + i] = run;
        cursor[base + i] = run;
        run += deg[base + i];
    }
    if (tid == 255) row_start[N_NODES] = run;
}

// scatter edges into dst-sorted order
__global__ __launch_bounds__(256) void scatter_kernel(const int* __restrict__ ei,
                                                      const float* __restrict__ ew,
                                                      int* __restrict__ cursor,
                                                      int* __restrict__ ssort,
                                                      float* __restrict__ wsort, int E) {
    int e = blockIdx.x * blockDim.x + threadIdx.x;
    if (e < E) {
        int d = ei[E + e];
        int pos = atomicAdd(&cursor[d], 1);
        ssort[pos] = ei[e];
        wsort[pos] = ew[e];
    }
}

// ---------------- fused: out[i] = relu(LN(sum_{e->i} w_e*H[src_e] + bias)) ----------------
__global__ __launch_bounds__(256) void agg_ln_csr(const int* __restrict__ row_start,
                                                  const int* __restrict__ ssort,
                                                  const float* __restrict__ wsort,
                                                  const float* __restrict__ H,
                                                  float* __restrict__ out,
                                                  const float* __restrict__ bias,
                                                  const float* __restrict__ g,
                                                  const float* __restrict__ b) {
    int wave = (blockIdx.x * blockDim.x + threadIdx.x) >> 6;
    int lane = threadIdx.x & 63;
    int s0 = row_start[wave], s1 = row_start[wave + 1];
    float ax0 = 0.f, ay0 = 0.f, ax1 = 0.f, ay1 = 0.f;
    int e = s0;
    for (; e + 1 < s1; e += 2) {
        int sA = ssort[e], sB = ssort[e + 1];
        float wA = wsort[e], wB = wsort[e + 1];
        float2 vA = *(const float2*)(H + (size_t)sA * 128 + lane * 2);
        float2 vB = *(const float2*)(H + (size_t)sB * 128 + lane * 2);
        ax0 += wA * vA.x; ay0 += wA * vA.y;
        ax1 += wB * vB.x; ay1 += wB * vB.y;
    }
    if (e < s1) {
        int sA = ssort[e];
        float wA = wsort[e];
        float2 vA = *(const float2*)(H + (size_t)sA * 128 + lane * 2);
        ax0 += wA * vA.x; ay0 += wA * vA.y;
    }
    float2 bs = *(const float2*)(bias + lane * 2);
    float vx = ax0 + ax1 + bs.x;
    float vy = ay0 + ay1 + bs.y;
    float s = vx + vy;
    float ss = vx * vx + vy * vy;
    for (int off = 32; off; off >>= 1) {
        s += __shfl_xor(s, off, 64);
        ss += __shfl_xor(ss, off, 64);
    }
    float mu = s * (1.f / 128.f);
    float var = ss * (1.f / 128.f) - mu * mu;
    float rs = rsqrtf(var + 1e-5f);
    float2 gg = *(const float2*)(g + lane * 2);
    float2 bb = *(const float2*)(b + lane * 2);
    float y0 = fmaxf((vx - mu) * rs * gg.x + bb.x, 0.f);
    float y1 = fmaxf((vy - mu) * rs * gg.y + bb.y, 0.f);
    *(float2*)(out + (size_t)wave * 128 + lane * 2) = make_float2(y0, y1);
}

// ---------------- pool0: one row per 8-lane group; c0 only (no xc0) ----------------
__global__ __launch_bounds__(256) void pool0_kernel(const float* __restrict__ latent,
                                                    const float* __restrict__ pW,
                                                    const float* __restrict__ pb,
                                                    const float* __restrict__ gum,
                                                    int* __restrict__ c0) {
    __shared__ float Ws[10 * 128];
    __shared__ float bs[10];
    for (int i = threadIdx.x; i < 1280; i += 256) Ws[i] = pW[i];
    if (threadIdx.x < 10) bs[threadIdx.x] = pb[threadIdx.x];
    __syncthreads();
    int lane = threadIdx.x & 63;
    int sub = lane & 7;                                   // 16-dim slice owner
    int row = (blockIdx.x * 4 + (threadIdx.x >> 6)) * 8 + (lane >> 3);

    const float4* lp = (const float4*)(latent + (size_t)row * 128 + sub * 16);
    float4 x0 = lp[0], x1 = lp[1], x2 = lp[2], x3 = lp[3];
    float2 gj[5];
    #pragma unroll
    for (int j = 0; j < 5; ++j) gj[j] = *(const float2*)(gum + (size_t)row * 10 + j * 2);

    float p[10];
    #pragma unroll
    for (int k = 0; k < 10; ++k) {
        const float4* wk = (const float4*)(Ws + k * 128 + sub * 16);
        float4 w0 = wk[0], w1 = wk[1], w2 = wk[2], w3 = wk[3];
        float a = x0.x * w0.x + x0.y * w0.y + x0.z * w0.z + x0.w * w0.w;
        a += x1.x * w1.x + x1.y * w1.y + x1.z * w1.z + x1.w * w1.w;
        a += x2.x * w2.x + x2.y * w2.y + x2.z * w2.z + x2.w * w2.w;
        a += x3.x * w3.x + x3.y * w3.y + x3.z * w3.z + x3.w * w3.w;
        p[k] = a;
    }
    #pragma unroll
    for (int off = 1; off < 8; off <<= 1) {
        #pragma unroll
        for (int k = 0; k < 10; ++k) p[k] += __shfl_xor(p[k], off, 64);
    }
    int best = 0;
    float bv = p[0] + bs[0] + gj[0].x;
    #pragma unroll
    for (int k = 1; k < 10; ++k) {
        float gk = (k & 1) ? gj[k >> 1].y : gj[k >> 1].x;
        float z = p[k] + bs[k] + gk;
        if (z > bv) { bv = z; best = k; }   // strict > : first max wins (jnp.argmax)
    }
    if (sub == 0) c0[row] = best;
}

// ---------------- xc0 partials: block (k, chunk) sums latent rows with c0==k ----------------
__global__ __launch_bounds__(256) void xc0_gather(const float* __restrict__ latent,
                                                  const int* __restrict__ c0,
                                                  float* __restrict__ partials) {
    int k = blockIdx.x >> 3;          // cluster
    int chunk = blockIdx.x & 7;       // row chunk
    int d = threadIdx.x & 127;
    int half = threadIdx.x >> 7;
    int rowbase = chunk * 1024 + half * 512;
    float acc = 0.f;
    for (int r = 0; r < 512; ++r) {
        int row = rowbase + r;
        if (c0[row] == k)             // wave-uniform branch
            acc += latent[(size_t)row * 128 + d];
    }
    __shared__ float part[256];
    part[threadIdx.x] = acc;
    __syncthreads();
    if (threadIdx.x < 128)
        partials[(size_t)(k * 8 + chunk) * 128 + d] = part[threadIdx.x] + part[threadIdx.x + 128];
}

// ---------------- A0[a,b] = sum_e w_e [c0[src]=a][c0[dst]=b] ----------------
__global__ __launch_bounds__(256) void adj_pool_kernel(const int* __restrict__ ei,
                                                       const float* __restrict__ ew,
                                                       const int* __restrict__ c0,
                                                       float* __restrict__ A0, int E) {
    __shared__ float As[100];
    for (int i = threadIdx.x; i < 100; i += 256) As[i] = 0.f;
    __syncthreads();
    const int* src = ei;
    const int* dst = ei + E;
    for (int e = blockIdx.x * blockDim.x + threadIdx.x; e < E; e += gridDim.x * blockDim.x) {
        int a = c0[src[e]], b = c0[dst[e]];
        atomicAdd(&As[a * 10 + b], ew[e]);
    }
    __syncthreads();
    for (int i = threadIdx.x; i < 100; i += 256) atomicAdd(&A0[i], As[i]);
}

// ---------------- single-block: levels 0/1 coarse math -> tbl[10][16] ----------------
__global__ __launch_bounds__(256) void small_kernel(const float* __restrict__ partials,
                                                    const float* __restrict__ A0,
                                                    const float* __restrict__ gum1,
                                                    const float* __restrict__ p1W,
                                                    const float* __restrict__ p1b,
                                                    const float* __restrict__ e0W,
                                                    const float* __restrict__ e0b,
                                                    const float* __restrict__ e1W,
                                                    const float* __restrict__ e1b,
                                                    const float* __restrict__ fcW,
                                                    const float* __restrict__ fcb,
                                                    float* __restrict__ tbl) {
    __shared__ float xc0n[10 * 128];
    __shared__ float adj0[100];
    __shared__ float m0[10 * 128];
    __shared__ float l1[10 * 128];
    __shared__ float xc1n[5 * 128];
    __shared__ float l2[5 * 128];
    __shared__ float A1[25];
    __shared__ int c1[10];
    __shared__ float red[4];

    int tid = threadIdx.x;
    int wid = tid >> 6, lane = tid & 63;

    // xc0 = sum of 8 chunk-partials
    for (int idx = tid; idx < 1280; idx += 256) {
        int r = idx >> 7, d = idx & 127;
        float s = 0.f;
        #pragma unroll
        for (int c = 0; c < 8; ++c) s += partials[(size_t)(r * 8 + c) * 128 + d];
        xc0n[idx] = s;
    }
    __syncthreads();
    // xc0 row-normalize (in place)
    for (int r = wid; r < 10; r += 4) {
        float2 v = *(const float2*)(xc0n + r * 128 + lane * 2);
        float ss = v.x * v.x + v.y * v.y;
        for (int off = 32; off; off >>= 1) ss += __shfl_xor(ss, off, 64);
        float sc = 1.f / fmaxf(sqrtf(ss), 1e-12f);
        xc0n[r * 128 + lane * 2] = v.x * sc;
        xc0n[r * 128 + lane * 2 + 1] = v.y * sc;
    }
    __syncthreads();
    // adj0 = A0 / (sum(A0) + 100*1e-8)
    if (tid == 0) {
        float s = 0.f;
        for (int i = 0; i < 100; ++i) s += A0[i];
        red[0] = s + 1e-6f;
    }
    __syncthreads();
    if (tid < 100) adj0[tid] = A0[tid] / red[0];
    __syncthreads();
    // m0 = adj0 @ xc0n
    for (int idx = tid; idx < 1280; idx += 256) {
        int r = idx >> 7, d = idx & 127;
        float acc = 0.f;
        #pragma unroll
        for (int a = 0; a < 10; ++a) acc += adj0[r * 10 + a] * xc0n[a * 128 + d];
        m0[idx] = acc;
    }
    __syncthreads();
    // l1 = relu(m0 @ e0W^T + e0b)
    for (int idx = tid; idx < 1280; idx += 256) {
        int r = idx >> 7, d = idx & 127;
        float acc = e0b[d];
        const float* wrow = e0W + d * 128;
        for (int k = 0; k < 128; ++k) acc += m0[r * 128 + k] * wrow[k];
        l1[idx] = fmaxf(acc, 0.f);
    }
    __syncthreads();
    // logits1 + gumbel1 argmax -> c1
    if (tid < 10) {
        int best = 0;
        float bv = -1e30f;
        for (int j = 0; j < 5; ++j) {
            float acc = p1b[j] + gum1[tid * 5 + j];
            const float* wrow = p1W + j * 128;
            for (int k = 0; k < 128; ++k) acc += l1[tid * 128 + k] * wrow[k];
            if (acc > bv) { bv = acc; best = j; }
        }
        c1[tid] = best;
    }
    __syncthreads();
    // xc1 = segsum(l1 by c1)
    for (int idx = tid; idx < 640; idx += 256) {
        int m = idx >> 7, d = idx & 127;
        float acc = 0.f;
        #pragma unroll
        for (int k = 0; k < 10; ++k)
            if (c1[k] == m) acc += l1[k * 128 + d];
        xc1n[idx] = acc;
    }
    __syncthreads();
    // normalize rows of xc1
    for (int r = wid; r < 5; r += 4) {
        float2 v = *(const float2*)(xc1n + r * 128 + lane * 2);
        float ss = v.x * v.x + v.y * v.y;
        for (int off = 32; off; off >>= 1) ss += __shfl_xor(ss, off, 64);
        float sc = 1.f / fmaxf(sqrtf(ss), 1e-12f);
        xc1n[r * 128 + lane * 2] = v.x * sc;
        xc1n[r * 128 + lane * 2 + 1] = v.y * sc;
    }
    __syncthreads();
    // A1[m,n] = sum_{a,b} adj0[a,b][c1[a]=m][c1[b]=n]
    if (tid < 25) {
        int m = tid / 5, n = tid % 5;
        float acc = 0.f;
        for (int a = 0; a < 10; ++a)
            for (int b = 0; b < 10; ++b)
                if (c1[a] == m && c1[b] == n) acc += adj0[a * 10 + b];
        A1[tid] = acc;
    }
    __syncthreads();
    if (tid == 0) {
        float s = 0.f;
        for (int i = 0; i < 25; ++i) s += A1[i];
        red[1] = s + 25e-8f;
    }
    __syncthreads();
    float den1 = red[1];
    // m1 = (A1/den1) @ xc1n   (reuse m0)
    for (int idx = tid; idx < 640; idx += 256) {
        int r = idx >> 7, d = idx & 127;
        float acc = 0.f;
        #pragma unroll
        for (int a = 0; a < 5; ++a) acc += A1[r * 5 + a] * xc1n[a * 128 + d];
        m0[idx] = acc / den1;
    }
    __syncthreads();
    // l2 = relu(m1 @ e1W^T + e1b)
    for (int idx = tid; idx < 640; idx += 256) {
        int r = idx >> 7, d = idx & 127;
        float acc = e1b[d];
        const float* wrow = e1W + d * 128;
        for (int k = 0; k < 128; ++k) acc += m0[r * 128 + k] * wrow[k];
        l2[idx] = fmaxf(acc, 0.f);
    }
    __syncthreads();
    // tbl[k][o] = fcb[o] + l1[k]·fcW[o,128:256] + l2[c1[k]]·fcW[o,256:384]
    for (int idx = tid; idx < 160; idx += 256) {
        int k = idx >> 4, o = idx & 15;
        float acc = fcb[o];
        const float* fB = fcW + o * 384 + 128;
        const float* fC = fcW + o * 384 + 256;
        const float* a1 = l1 + k * 128;
        const float* a2 = l2 + c1[k] * 128;
        for (int d = 0; d < 128; ++d) acc += a1[d] * fB[d] + a2[d] * fC[d];
        tbl[idx] = acc;
    }
}

// ---------------- out[i] = latent[i] @ fcA^T + tbl[c0[i]] ----------------
__global__ __launch_bounds__(256) void out_kernel(const float* __restrict__ latent,
                                                  const int* __restrict__ c0,
                                                  const float* __restrict__ tbl,
                                                  const float* __restrict__ fcW,
                                                  float* __restrict__ out, int nrows) {
    __shared__ float fA[16 * 128];
    __shared__ float ts[160];
    for (int i = threadIdx.x; i < 2048; i += 256) {
        int o = i >> 7, d = i & 127;
        fA[i] = fcW[o * 384 + d];
    }
    for (int i = threadIdx.x; i < 160; i += 256) ts[i] = tbl[i];
    __syncthreads();
    int wid = threadIdx.x >> 6, lane = threadIdx.x & 63;
    int row = blockIdx.x * 4 + wid;
    if (row >= nrows) return;
    float2 x = *(const float2*)(latent + (size_t)row * 128 + lane * 2);
    float p[16];
    #pragma unroll
    for (int o = 0; o < 16; ++o)
        p[o] = x.x * fA[o * 128 + lane * 2] + x.y * fA[o * 128 + lane * 2 + 1];
    for (int off = 32; off; off >>= 1) {
        #pragma unroll
        for (int o = 0; o < 16; ++o) p[o] += __shfl_xor(p[o], off, 64);
    }
    if (lane < 16) {
        int c = c0[row];
        out[(size_t)row * 16 + lane] = p[lane] + ts[c * 16 + lane];
    }
}

extern "C" void kernel_launch(void* const* d_in, const int* in_sizes, int n_in,
                              void* d_out, int out_size, void* d_ws, size_t ws_size,
                              hipStream_t stream) {
    const float* x    = (const float*)d_in[0];
    const int*   ei   = (const int*)d_in[1];
    const float* ew   = (const float*)d_in[2];
    const float* g0   = (const float*)d_in[3];
    const float* g1   = (const float*)d_in[4];
    const float* Wg1  = (const float*)d_in[5];
    const float* bg1  = (const float*)d_in[6];
    const float* ln1g = (const float*)d_in[7];
    const float* ln1b = (const float*)d_in[8];
    const float* Wg2  = (const float*)d_in[9];
    const float* bg2  = (const float*)d_in[10];
    const float* ln2g = (const float*)d_in[11];
    const float* ln2b = (const float*)d_in[12];
    const float* p0W  = (const float*)d_in[13];
    const float* p0b  = (const float*)d_in[14];
    const float* p1W  = (const float*)d_in[15];
    const float* p1b  = (const float*)d_in[16];
    const float* e0W  = (const float*)d_in[17];
    const float* e0b  = (const float*)d_in[18];
    const float* e1W  = (const float*)d_in[19];
    const float* e1b  = (const float*)d_in[20];
    const float* fcW  = (const float*)d_in[21];
    const float* fcb  = (const float*)d_in[22];
    float* out = (float*)d_out;

    float* ws   = (float*)d_ws;
    float* bufA = ws;                                        // N*128 f
    float* bufB = bufA + (size_t)N_NODES * 128;              // N*128 f
    int*   c0   = (int*)(bufB + (size_t)N_NODES * 128);      // N int
    float* A0   = (float*)(c0 + N_NODES);                    // 100 f
    float* tbl  = A0 + 100;                                  // 160 f
    float* partials = tbl + 160;                             // 10*8*128 f
    int*   deg  = (int*)(partials + 10 * 8 * 128);           // N int
    int*   row_start = deg + N_NODES;                        // N+1 int
    int*   cursor    = row_start + N_NODES + 1;              // N int
    int*   ssort     = cursor + N_NODES;                     // E int
    float* wsort     = (float*)(ssort + N_EDGES);            // E f

    // ---- build CSR (dst-sorted edges), reused by both layers ----
    hipMemsetAsync(deg, 0, N_NODES * sizeof(int), stream);
    hist_kernel<<<256, 256, 0, stream>>>(ei, deg, N_EDGES);
    scan_kernel<<<1, 256, 0, stream>>>(deg, row_start, cursor);
    scatter_kernel<<<N_EDGES / 256, 256, 0, stream>>>(ei, ew, cursor, ssort, wsort, N_EDGES);

    // layer 1: agg(x) @ Wg1^T == agg(x @ Wg1^T); then fused +bias, LN, relu
    gemm_rows<NFEAT><<<N_NODES / 8, 128, 0, stream>>>(x, Wg1, bufA, N_NODES);
    agg_ln_csr<<<N_NODES / 4, 256, 0, stream>>>(row_start, ssort, wsort, bufA, bufB,
                                                bg1, ln1g, ln1b);

    // layer 2
    gemm_rows<NHID><<<N_NODES / 8, 128, 0, stream>>>(bufB, Wg2, bufA, N_NODES);
    agg_ln_csr<<<N_NODES / 4, 256, 0, stream>>>(row_start, ssort, wsort, bufA, bufB,
                                                bg2, ln2g, ln2b);
    // bufB = latent [N,128]

    // level 0 pooling: c0 (8-lane groups), then non-atomic xc0 partials + A0
    pool0_kernel<<<256, 256, 0, stream>>>(bufB, p0W, p0b, g0, c0);
    xc0_gather<<<80, 256, 0, stream>>>(bufB, c0, partials);
    hipMemsetAsync(A0, 0, 100 * sizeof(float), stream);
    adj_pool_kernel<<<256, 256, 0, stream>>>(ei, ew, c0, A0, N_EDGES);

    // coarse levels -> tbl
    small_kernel<<<1, 256, 0, stream>>>(partials, A0, g1, p1W, p1b, e0W, e0b, e1W, e1b,
                                        fcW, fcb, tbl);

    // final: out = latent @ fcA^T + tbl[c0]
    out_kernel<<<N_NODES / 4, 256, 0, stream>>>(bufB, c0, tbl, fcW, out, N_NODES);
}

// Round 5
// 211.628 us; speedup vs baseline: 1.2369x; 1.2369x over previous
//
#include <hip/hip_runtime.h>

#define N_NODES 8192
#define N_EDGES 262144
#define NFEAT 200
#define NHID 128

// ---------------- GEMM: C[nrows,128] = A[nrows,K] @ W[128,K]^T ----------------
template<int K>
__global__ __launch_bounds__(128) void gemm_rows(const float* __restrict__ A,
                                                 const float* __restrict__ W,
                                                 float* __restrict__ C,
                                                 int nrows) {
    __shared__ float a_s[8 * K];
    int row0 = blockIdx.x * 8;
    const float* Ab = A + (size_t)row0 * K;
    for (int idx = threadIdx.x; idx < 8 * K; idx += 128) a_s[idx] = Ab[idx];
    __syncthreads();
    int j = threadIdx.x;
    float acc[8] = {0.f, 0.f, 0.f, 0.f, 0.f, 0.f, 0.f, 0.f};
    const float4* W4 = (const float4*)(W + (size_t)j * K);
    for (int k4 = 0; k4 < K / 4; ++k4) {
        float4 w = W4[k4];
        int k = k4 * 4;
        #pragma unroll
        for (int r = 0; r < 8; ++r) {
            const float* ar = a_s + r * K + k;
            acc[r] += ar[0] * w.x + ar[1] * w.y + ar[2] * w.z + ar[3] * w.w;
        }
    }
    #pragma unroll
    for (int r = 0; r < 8; ++r) C[(size_t)(row0 + r) * 128 + j] = acc[r];
}

// ---------------- CSR build: histogram of dst ----------------
__global__ __launch_bounds__(256) void hist_kernel(const int* __restrict__ ei,
                                                   int* __restrict__ deg, int E) {
    const int* dst = ei + E;
    for (int e = blockIdx.x * blockDim.x + threadIdx.x; e < E; e += gridDim.x * blockDim.x)
        atomicAdd(&deg[dst[e]], 1);
}

// single block, 256 threads: exclusive prefix sum of deg[8192] -> row_start, cursor
__global__ __launch_bounds__(256) void scan_kernel(const int* __restrict__ deg,
                                                   int* __restrict__ row_start,
                                                   int* __restrict__ cursor) {
    __shared__ int part[256];
    __shared__ int partx[257];
    int tid = threadIdx.x;
    int base = tid * 32;
    int s = 0;
    for (int i = 0; i < 32; ++i) s += deg[base + i];
    part[tid] = s;
    __syncthreads();
    if (tid == 0) {
        int run = 0;
        for (int i = 0; i < 256; ++i) { partx[i] = run; run += part[i]; }
        partx[256] = run;
    }
    __syncthreads();
    int run = partx[tid];
    for (int i = 0; i < 32; ++i) {
        row_start[base + i] = run;
        cursor[base + i] = run;
        run += deg[base + i];
    }
    if (tid == 255) row_start[N_NODES] = run;
}

// scatter edges into dst-sorted order
__global__ __launch_bounds__(256) void scatter_kernel(const int* __restrict__ ei,
                                                      const float* __restrict__ ew,
                                                      int* __restrict__ cursor,
                                                      int* __restrict__ ssort,
                                                      float* __restrict__ wsort, int E) {
    int e = blockIdx.x * blockDim.x + threadIdx.x;
    if (e < E) {
        int d = ei[E + e];
        int pos = atomicAdd(&cursor[d], 1);
        ssort[pos] = ei[e];
        wsort[pos] = ew[e];
    }
}

// ---------------- fused: out[i] = relu(LN(sum_{e->i} w_e*H[src_e] + bias)) ----------------
__global__ __launch_bounds__(256) void agg_ln_csr(const int* __restrict__ row_start,
                                                  const int* __restrict__ ssort,
                                                  const float* __restrict__ wsort,
                                                  const float* __restrict__ H,
                                                  float* __restrict__ out,
                                                  const float* __restrict__ bias,
                                                  const float* __restrict__ g,
                                                  const float* __restrict__ b) {
    int wave = (blockIdx.x * blockDim.x + threadIdx.x) >> 6;
    int lane = threadIdx.x & 63;
    int s0 = row_start[wave], s1 = row_start[wave + 1];
    float ax0 = 0.f, ay0 = 0.f, ax1 = 0.f, ay1 = 0.f;
    int e = s0;
    for (; e + 1 < s1; e += 2) {
        int sA = ssort[e], sB = ssort[e + 1];
        float wA = wsort[e], wB = wsort[e + 1];
        float2 vA = *(const float2*)(H + (size_t)sA * 128 + lane * 2);
        float2 vB = *(const float2*)(H + (size_t)sB * 128 + lane * 2);
        ax0 += wA * vA.x; ay0 += wA * vA.y;
        ax1 += wB * vB.x; ay1 += wB * vB.y;
    }
    if (e < s1) {
        int sA = ssort[e];
        float wA = wsort[e];
        float2 vA = *(const float2*)(H + (size_t)sA * 128 + lane * 2);
        ax0 += wA * vA.x; ay0 += wA * vA.y;
    }
    float2 bs = *(const float2*)(bias + lane * 2);
    float vx = ax0 + ax1 + bs.x;
    float vy = ay0 + ay1 + bs.y;
    float s = vx + vy;
    float ss = vx * vx + vy * vy;
    for (int off = 32; off; off >>= 1) {
        s += __shfl_xor(s, off, 64);
        ss += __shfl_xor(ss, off, 64);
    }
    float mu = s * (1.f / 128.f);
    float var = ss * (1.f / 128.f) - mu * mu;
    float rs = rsqrtf(var + 1e-5f);
    float2 gg = *(const float2*)(g + lane * 2);
    float2 bb = *(const float2*)(b + lane * 2);
    float y0 = fmaxf((vx - mu) * rs * gg.x + bb.x, 0.f);
    float y1 = fmaxf((vy - mu) * rs * gg.y + bb.y, 0.f);
    *(float2*)(out + (size_t)wave * 128 + lane * 2) = make_float2(y0, y1);
}

// ---------------- pool0: one row per 8-lane group; c0 only ----------------
__global__ __launch_bounds__(256) void pool0_kernel(const float* __restrict__ latent,
                                                    const float* __restrict__ pW,
                                                    const float* __restrict__ pb,
                                                    const float* __restrict__ gum,
                                                    int* __restrict__ c0) {
    __shared__ float Ws[10 * 128];
    __shared__ float bs[10];
    for (int i = threadIdx.x; i < 1280; i += 256) Ws[i] = pW[i];
    if (threadIdx.x < 10) bs[threadIdx.x] = pb[threadIdx.x];
    __syncthreads();
    int lane = threadIdx.x & 63;
    int sub = lane & 7;                                   // 16-dim slice owner
    int row = (blockIdx.x * 4 + (threadIdx.x >> 6)) * 8 + (lane >> 3);

    const float4* lp = (const float4*)(latent + (size_t)row * 128 + sub * 16);
    float4 x0 = lp[0], x1 = lp[1], x2 = lp[2], x3 = lp[3];
    float2 gj[5];
    #pragma unroll
    for (int j = 0; j < 5; ++j) gj[j] = *(const float2*)(gum + (size_t)row * 10 + j * 2);

    float p[10];
    #pragma unroll
    for (int k = 0; k < 10; ++k) {
        const float4* wk = (const float4*)(Ws + k * 128 + sub * 16);
        float4 w0 = wk[0], w1 = wk[1], w2 = wk[2], w3 = wk[3];
        float a = x0.x * w0.x + x0.y * w0.y + x0.z * w0.z + x0.w * w0.w;
        a += x1.x * w1.x + x1.y * w1.y + x1.z * w1.z + x1.w * w1.w;
        a += x2.x * w2.x + x2.y * w2.y + x2.z * w2.z + x2.w * w2.w;
        a += x3.x * w3.x + x3.y * w3.y + x3.z * w3.z + x3.w * w3.w;
        p[k] = a;
    }
    #pragma unroll
    for (int off = 1; off < 8; off <<= 1) {
        #pragma unroll
        for (int k = 0; k < 10; ++k) p[k] += __shfl_xor(p[k], off, 64);
    }
    int best = 0;
    float bv = p[0] + bs[0] + gj[0].x;
    #pragma unroll
    for (int k = 1; k < 10; ++k) {
        float gk = (k & 1) ? gj[k >> 1].y : gj[k >> 1].x;
        float z = p[k] + bs[k] + gk;
        if (z > bv) { bv = z; best = k; }   // strict > : first max wins (jnp.argmax)
    }
    if (sub == 0) c0[row] = best;
}

// ---------------- xc0 partials: 256 blocks, 32 rows each, LDS accumulate ----------------
__global__ __launch_bounds__(256) void xc0_partial(const float* __restrict__ latent,
                                                   const int* __restrict__ c0,
                                                   float* __restrict__ partials) {
    __shared__ float acc[1280];
    for (int i = threadIdx.x; i < 1280; i += 256) acc[i] = 0.f;
    __syncthreads();
    int d = threadIdx.x & 127;
    int half = threadIdx.x >> 7;          // 0..1 -> 2 rows in flight
    int base = blockIdx.x * 32;
    #pragma unroll
    for (int it = 0; it < 16; ++it) {
        int row = base + it * 2 + half;
        int c = c0[row];
        float v = latent[(size_t)row * 128 + d];
        atomicAdd(&acc[c * 128 + d], v);  // LDS atomic, no return -> no dep chain
    }
    __syncthreads();
    for (int i = threadIdx.x; i < 1280; i += 256)
        partials[(size_t)blockIdx.x * 1280 + i] = acc[i];
}

// ---------------- xc0[k] = sum over 256 partial blocks ----------------
__global__ __launch_bounds__(256) void xc0_reduce(const float* __restrict__ partials,
                                                  float* __restrict__ xc0) {
    int k = blockIdx.x;
    int d = threadIdx.x & 127;
    int half = threadIdx.x >> 7;
    int b0 = half * 128;
    float s0 = 0.f, s1 = 0.f, s2 = 0.f, s3 = 0.f;
    for (int b = b0; b < b0 + 128; b += 4) {
        s0 += partials[(size_t)(b    ) * 1280 + k * 128 + d];
        s1 += partials[(size_t)(b + 1) * 1280 + k * 128 + d];
        s2 += partials[(size_t)(b + 2) * 1280 + k * 128 + d];
        s3 += partials[(size_t)(b + 3) * 1280 + k * 128 + d];
    }
    __shared__ float sm[256];
    sm[threadIdx.x] = (s0 + s1) + (s2 + s3);
    __syncthreads();
    if (threadIdx.x < 128) xc0[k * 128 + d] = sm[threadIdx.x] + sm[threadIdx.x + 128];
}

// ---------------- A0[a,b] = sum_e w_e [c0[src]=a][c0[dst]=b] ----------------
__global__ __launch_bounds__(256) void adj_pool_kernel(const int* __restrict__ ei,
                                                       const float* __restrict__ ew,
                                                       const int* __restrict__ c0,
                                                       float* __restrict__ A0, int E) {
    __shared__ float As[100];
    for (int i = threadIdx.x; i < 100; i += 256) As[i] = 0.f;
    __syncthreads();
    const int* src = ei;
    const int* dst = ei + E;
    for (int e = blockIdx.x * blockDim.x + threadIdx.x; e < E; e += gridDim.x * blockDim.x) {
        int a = c0[src[e]], b = c0[dst[e]];
        atomicAdd(&As[a * 10 + b], ew[e]);
    }
    __syncthreads();
    for (int i = threadIdx.x; i < 100; i += 256) atomicAdd(&A0[i], As[i]);
}

// ---------------- single-block: levels 0/1 coarse math -> tbl[10][16] ----------------
__global__ __launch_bounds__(256) void small_kernel(const float* __restrict__ xc0,
                                                    const float* __restrict__ A0,
                                                    const float* __restrict__ gum1,
                                                    const float* __restrict__ p1W,
                                                    const float* __restrict__ p1b,
                                                    const float* __restrict__ e0W,
                                                    const float* __restrict__ e0b,
                                                    const float* __restrict__ e1W,
                                                    const float* __restrict__ e1b,
                                                    const float* __restrict__ fcW,
                                                    const float* __restrict__ fcb,
                                                    float* __restrict__ tbl) {
    __shared__ float xc0n[10 * 128];
    __shared__ float adj0[100];
    __shared__ float m0[10 * 128];
    __shared__ float l1[10 * 128];
    __shared__ float xc1n[5 * 128];
    __shared__ float l2[5 * 128];
    __shared__ float A1[25];
    __shared__ int c1[10];
    __shared__ float red[4];

    int tid = threadIdx.x;
    int wid = tid >> 6, lane = tid & 63;

    // xc0 row-normalize
    for (int r = wid; r < 10; r += 4) {
        float2 v = *(const float2*)(xc0 + r * 128 + lane * 2);
        float ss = v.x * v.x + v.y * v.y;
        for (int off = 32; off; off >>= 1) ss += __shfl_xor(ss, off, 64);
        float sc = 1.f / fmaxf(sqrtf(ss), 1e-12f);
        xc0n[r * 128 + lane * 2] = v.x * sc;
        xc0n[r * 128 + lane * 2 + 1] = v.y * sc;
    }
    __syncthreads();
    // adj0 = A0 / (sum(A0) + 100*1e-8)
    if (tid == 0) {
        float s = 0.f;
        for (int i = 0; i < 100; ++i) s += A0[i];
        red[0] = s + 1e-6f;
    }
    __syncthreads();
    if (tid < 100) adj0[tid] = A0[tid] / red[0];
    __syncthreads();
    // m0 = adj0 @ xc0n
    for (int idx = tid; idx < 1280; idx += 256) {
        int r = idx >> 7, d = idx & 127;
        float acc = 0.f;
        #pragma unroll
        for (int a = 0; a < 10; ++a) acc += adj0[r * 10 + a] * xc0n[a * 128 + d];
        m0[idx] = acc;
    }
    __syncthreads();
    // l1 = relu(m0 @ e0W^T + e0b)
    for (int idx = tid; idx < 1280; idx += 256) {
        int r = idx >> 7, d = idx & 127;
        float acc = e0b[d];
        const float* wrow = e0W + d * 128;
        for (int k = 0; k < 128; ++k) acc += m0[r * 128 + k] * wrow[k];
        l1[idx] = fmaxf(acc, 0.f);
    }
    __syncthreads();
    // logits1 + gumbel1 argmax -> c1
    if (tid < 10) {
        int best = 0;
        float bv = -1e30f;
        for (int j = 0; j < 5; ++j) {
            float acc = p1b[j] + gum1[tid * 5 + j];
            const float* wrow = p1W + j * 128;
            for (int k = 0; k < 128; ++k) acc += l1[tid * 128 + k] * wrow[k];
            if (acc > bv) { bv = acc; best = j; }
        }
        c1[tid] = best;
    }
    __syncthreads();
    // xc1 = segsum(l1 by c1)
    for (int idx = tid; idx < 640; idx += 256) {
        int m = idx >> 7, d = idx & 127;
        float acc = 0.f;
        #pragma unroll
        for (int k = 0; k < 10; ++k)
            if (c1[k] == m) acc += l1[k * 128 + d];
        xc1n[idx] = acc;
    }
    __syncthreads();
    // normalize rows of xc1
    for (int r = wid; r < 5; r += 4) {
        float2 v = *(const float2*)(xc1n + r * 128 + lane * 2);
        float ss = v.x * v.x + v.y * v.y;
        for (int off = 32; off; off >>= 1) ss += __shfl_xor(ss, off, 64);
        float sc = 1.f / fmaxf(sqrtf(ss), 1e-12f);
        xc1n[r * 128 + lane * 2] = v.x * sc;
        xc1n[r * 128 + lane * 2 + 1] = v.y * sc;
    }
    __syncthreads();
    // A1[m,n] = sum_{a,b} adj0[a,b][c1[a]=m][c1[b]=n]
    if (tid < 25) {
        int m = tid / 5, n = tid % 5;
        float acc = 0.f;
        for (int a = 0; a < 10; ++a)
            for (int b = 0; b < 10; ++b)
                if (c1[a] == m && c1[b] == n) acc += adj0[a * 10 + b];
        A1[tid] = acc;
    }
    __syncthreads();
    if (tid == 0) {
        float s = 0.f;
        for (int i = 0; i < 25; ++i) s += A1[i];
        red[1] = s + 25e-8f;
    }
    __syncthreads();
    float den1 = red[1];
    // m1 = (A1/den1) @ xc1n   (reuse m0)
    for (int idx = tid; idx < 640; idx += 256) {
        int r = idx >> 7, d = idx & 127;
        float acc = 0.f;
        #pragma unroll
        for (int a = 0; a < 5; ++a) acc += A1[r * 5 + a] * xc1n[a * 128 + d];
        m0[idx] = acc / den1;
    }
    __syncthreads();
    // l2 = relu(m1 @ e1W^T + e1b)
    for (int idx = tid; idx < 640; idx += 256) {
        int r = idx >> 7, d = idx & 127;
        float acc = e1b[d];
        const float* wrow = e1W + d * 128;
        for (int k = 0; k < 128; ++k) acc += m0[r * 128 + k] * wrow[k];
        l2[idx] = fmaxf(acc, 0.f);
    }
    __syncthreads();
    // tbl[k][o] = fcb[o] + l1[k]·fcW[o,128:256] + l2[c1[k]]·fcW[o,256:384]
    for (int idx = tid; idx < 160; idx += 256) {
        int k = idx >> 4, o = idx & 15;
        float acc = fcb[o];
        const float* fB = fcW + o * 384 + 128;
        const float* fC = fcW + o * 384 + 256;
        const float* a1 = l1 + k * 128;
        const float* a2 = l2 + c1[k] * 128;
        for (int d = 0; d < 128; ++d) acc += a1[d] * fB[d] + a2[d] * fC[d];
        tbl[idx] = acc;
    }
}

// ---------------- out[i] = latent[i] @ fcA^T + tbl[c0[i]] ----------------
__global__ __launch_bounds__(256) void out_kernel(const float* __restrict__ latent,
                                                  const int* __restrict__ c0,
                                                  const float* __restrict__ tbl,
                                                  const float* __restrict__ fcW,
                                                  float* __restrict__ out, int nrows) {
    __shared__ float fA[16 * 128];
    __shared__ float ts[160];
    for (int i = threadIdx.x; i < 2048; i += 256) {
        int o = i >> 7, d = i & 127;
        fA[i] = fcW[o * 384 + d];
    }
    for (int i = threadIdx.x; i < 160; i += 256) ts[i] = tbl[i];
    __syncthreads();
    int wid = threadIdx.x >> 6, lane = threadIdx.x & 63;
    int row = blockIdx.x * 4 + wid;
    if (row >= nrows) return;
    float2 x = *(const float2*)(latent + (size_t)row * 128 + lane * 2);
    float p[16];
    #pragma unroll
    for (int o = 0; o < 16; ++o)
        p[o] = x.x * fA[o * 128 + lane * 2] + x.y * fA[o * 128 + lane * 2 + 1];
    for (int off = 32; off; off >>= 1) {
        #pragma unroll
        for (int o = 0; o < 16; ++o) p[o] += __shfl_xor(p[o], off, 64);
    }
    if (lane < 16) {
        int c = c0[row];
        out[(size_t)row * 16 + lane] = p[lane] + ts[c * 16 + lane];
    }
}

extern "C" void kernel_launch(void* const* d_in, const int* in_sizes, int n_in,
                              void* d_out, int out_size, void* d_ws, size_t ws_size,
                              hipStream_t stream) {
    const float* x    = (const float*)d_in[0];
    const int*   ei   = (const int*)d_in[1];
    const float* ew   = (const float*)d_in[2];
    const float* g0   = (const float*)d_in[3];
    const float* g1   = (const float*)d_in[4];
    const float* Wg1  = (const float*)d_in[5];
    const float* bg1  = (const float*)d_in[6];
    const float* ln1g = (const float*)d_in[7];
    const float* ln1b = (const float*)d_in[8];
    const float* Wg2  = (const float*)d_in[9];
    const float* bg2  = (const float*)d_in[10];
    const float* ln2g = (const float*)d_in[11];
    const float* ln2b = (const float*)d_in[12];
    const float* p0W  = (const float*)d_in[13];
    const float* p0b  = (const float*)d_in[14];
    const float* p1W  = (const float*)d_in[15];
    const float* p1b  = (const float*)d_in[16];
    const float* e0W  = (const float*)d_in[17];
    const float* e0b  = (const float*)d_in[18];
    const float* e1W  = (const float*)d_in[19];
    const float* e1b  = (const float*)d_in[20];
    const float* fcW  = (const float*)d_in[21];
    const float* fcb  = (const float*)d_in[22];
    float* out = (float*)d_out;

    float* ws   = (float*)d_ws;
    float* bufA = ws;                                        // N*128 f
    float* bufB = bufA + (size_t)N_NODES * 128;              // N*128 f
    int*   c0   = (int*)(bufB + (size_t)N_NODES * 128);      // N int
    float* xc0  = (float*)(c0 + N_NODES);                    // 1280 f
    float* A0   = xc0 + 1280;                                // 100 f
    float* tbl  = A0 + 100;                                  // 160 f
    int*   deg  = (int*)(tbl + 160);                         // N int
    int*   row_start = deg + N_NODES;                        // N+1 int
    int*   cursor    = row_start + N_NODES + 1;              // N int
    int*   ssort     = cursor + N_NODES;                     // E int
    float* wsort     = (float*)(ssort + N_EDGES);            // E f
    float* partials  = bufA;   // 256*1280 f = 1.31 MB, reuses bufA (free after 2nd agg)

    // ---- build CSR (dst-sorted edges), reused by both layers ----
    hipMemsetAsync(deg, 0, N_NODES * sizeof(int), stream);
    hist_kernel<<<256, 256, 0, stream>>>(ei, deg, N_EDGES);
    scan_kernel<<<1, 256, 0, stream>>>(deg, row_start, cursor);
    scatter_kernel<<<N_EDGES / 256, 256, 0, stream>>>(ei, ew, cursor, ssort, wsort, N_EDGES);

    // layer 1: agg(x) @ Wg1^T == agg(x @ Wg1^T); then fused +bias, LN, relu
    gemm_rows<NFEAT><<<N_NODES / 8, 128, 0, stream>>>(x, Wg1, bufA, N_NODES);
    agg_ln_csr<<<N_NODES / 4, 256, 0, stream>>>(row_start, ssort, wsort, bufA, bufB,
                                                bg1, ln1g, ln1b);

    // layer 2
    gemm_rows<NHID><<<N_NODES / 8, 128, 0, stream>>>(bufB, Wg2, bufA, N_NODES);
    agg_ln_csr<<<N_NODES / 4, 256, 0, stream>>>(row_start, ssort, wsort, bufA, bufB,
                                                bg2, ln2g, ln2b);
    // bufB = latent [N,128]; bufA now free -> partials

    // level 0 pooling: c0, then non-atomic xc0 partials + reduce, + A0
    pool0_kernel<<<256, 256, 0, stream>>>(bufB, p0W, p0b, g0, c0);
    xc0_partial<<<256, 256, 0, stream>>>(bufB, c0, partials);
    xc0_reduce<<<10, 256, 0, stream>>>(partials, xc0);
    hipMemsetAsync(A0, 0, 100 * sizeof(float), stream);
    adj_pool_kernel<<<256, 256, 0, stream>>>(ei, ew, c0, A0, N_EDGES);

    // coarse levels -> tbl
    small_kernel<<<1, 256, 0, stream>>>(xc0, A0, g1, p1W, p1b, e0W, e0b, e1W, e1b,
                                        fcW, fcb, tbl);

    // final: out = latent @ fcA^T + tbl[c0]
    out_kernel<<<N_NODES / 4, 256, 0, stream>>>(bufB, c0, tbl, fcW, out, N_NODES);
}

// Round 6
// 181.272 us; speedup vs baseline: 1.4440x; 1.1675x over previous
//
#include <hip/hip_runtime.h>

#define N_NODES 8192
#define N_EDGES 262144
#define NFEAT 200
#define NHID 128

// ---------------- GEMM body: C[8 rows,128] = A[8,K] @ W[128,K]^T ----------------
template<int K>
__device__ __forceinline__ void gemm_body(const float* __restrict__ A,
                                          const float* __restrict__ W,
                                          float* __restrict__ C, int bid) {
    __shared__ float a_s[8 * K];
    int row0 = bid * 8;
    const float* Ab = A + (size_t)row0 * K;
    for (int idx = threadIdx.x; idx < 8 * K; idx += 128) a_s[idx] = Ab[idx];
    __syncthreads();
    int j = threadIdx.x;
    float acc[8] = {0.f, 0.f, 0.f, 0.f, 0.f, 0.f, 0.f, 0.f};
    const float4* W4 = (const float4*)(W + (size_t)j * K);
    for (int k4 = 0; k4 < K / 4; ++k4) {
        float4 w = W4[k4];
        int k = k4 * 4;
        #pragma unroll
        for (int r = 0; r < 8; ++r) {
            const float* ar = a_s + r * K + k;
            acc[r] += ar[0] * w.x + ar[1] * w.y + ar[2] * w.z + ar[3] * w.w;
        }
    }
    #pragma unroll
    for (int r = 0; r < 8; ++r) C[(size_t)(row0 + r) * 128 + j] = acc[r];
}

template<int K>
__global__ __launch_bounds__(128) void gemm_rows(const float* __restrict__ A,
                                                 const float* __restrict__ W,
                                                 float* __restrict__ C) {
    gemm_body<K>(A, W, C, blockIdx.x);
}

// fused: blocks [0,1024) gemm layer-1; blocks [1024,1088) histogram of dst (independent)
__global__ __launch_bounds__(128) void gemm1_hist(const float* __restrict__ A,
                                                  const float* __restrict__ W,
                                                  float* __restrict__ C,
                                                  const int* __restrict__ ei,
                                                  int* __restrict__ deg) {
    if (blockIdx.x < N_NODES / 8) {
        gemm_body<NFEAT>(A, W, C, blockIdx.x);
    } else {
        const int* dst = ei + N_EDGES;
        for (int e = (blockIdx.x - N_NODES / 8) * 128 + threadIdx.x; e < N_EDGES; e += 64 * 128)
            atomicAdd(&deg[dst[e]], 1);
    }
}

// single block, 256 threads: exclusive prefix sum of deg[8192] -> row_start, cursor
__global__ __launch_bounds__(256) void scan_kernel(const int* __restrict__ deg,
                                                   int* __restrict__ row_start,
                                                   int* __restrict__ cursor) {
    __shared__ int part[256];
    __shared__ int partx[257];
    int tid = threadIdx.x;
    int base = tid * 32;
    int s = 0;
    for (int i = 0; i < 32; ++i) s += deg[base + i];
    part[tid] = s;
    __syncthreads();
    if (tid == 0) {
        int run = 0;
        for (int i = 0; i < 256; ++i) { partx[i] = run; run += part[i]; }
        partx[256] = run;
    }
    __syncthreads();
    int run = partx[tid];
    for (int i = 0; i < 32; ++i) {
        row_start[base + i] = run;
        cursor[base + i] = run;
        run += deg[base + i];
    }
    if (tid == 255) row_start[N_NODES] = run;
}

// scatter edges into dst-sorted order, packed (src, weight-bits)
__global__ __launch_bounds__(256) void scatter_kernel(const int* __restrict__ ei,
                                                      const float* __restrict__ ew,
                                                      int* __restrict__ cursor,
                                                      int2* __restrict__ esort, int E) {
    int e = blockIdx.x * blockDim.x + threadIdx.x;
    if (e < E) {
        int d = ei[E + e];
        int pos = atomicAdd(&cursor[d], 1);
        esort[pos] = make_int2(ei[e], __float_as_int(ew[e]));
    }
}

// ---------------- fused: out[i] = relu(LN(sum_{e->i} w_e*H[src_e] + bias)) ----------------
__global__ __launch_bounds__(256) void agg_ln_csr(const int* __restrict__ row_start,
                                                  const int2* __restrict__ esort,
                                                  const float* __restrict__ H,
                                                  float* __restrict__ out,
                                                  const float* __restrict__ bias,
                                                  const float* __restrict__ g,
                                                  const float* __restrict__ b) {
    int wave = (blockIdx.x * blockDim.x + threadIdx.x) >> 6;
    int lane = threadIdx.x & 63;
    int s0 = row_start[wave], s1 = row_start[wave + 1];
    float ax0 = 0.f, ay0 = 0.f, ax1 = 0.f, ay1 = 0.f;
    float ax2 = 0.f, ay2 = 0.f, ax3 = 0.f, ay3 = 0.f;
    int e = s0;
    for (; e + 3 < s1; e += 4) {
        int2 p0 = esort[e], p1 = esort[e + 1], p2 = esort[e + 2], p3 = esort[e + 3];
        float2 v0 = *(const float2*)(H + (size_t)p0.x * 128 + lane * 2);
        float2 v1 = *(const float2*)(H + (size_t)p1.x * 128 + lane * 2);
        float2 v2 = *(const float2*)(H + (size_t)p2.x * 128 + lane * 2);
        float2 v3 = *(const float2*)(H + (size_t)p3.x * 128 + lane * 2);
        float w0 = __int_as_float(p0.y), w1 = __int_as_float(p1.y);
        float w2 = __int_as_float(p2.y), w3 = __int_as_float(p3.y);
        ax0 += w0 * v0.x; ay0 += w0 * v0.y;
        ax1 += w1 * v1.x; ay1 += w1 * v1.y;
        ax2 += w2 * v2.x; ay2 += w2 * v2.y;
        ax3 += w3 * v3.x; ay3 += w3 * v3.y;
    }
    for (; e < s1; ++e) {
        int2 p0 = esort[e];
        float2 v0 = *(const float2*)(H + (size_t)p0.x * 128 + lane * 2);
        float w0 = __int_as_float(p0.y);
        ax0 += w0 * v0.x; ay0 += w0 * v0.y;
    }
    float2 bs = *(const float2*)(bias + lane * 2);
    float vx = (ax0 + ax1) + (ax2 + ax3) + bs.x;
    float vy = (ay0 + ay1) + (ay2 + ay3) + bs.y;
    float s = vx + vy;
    float ss = vx * vx + vy * vy;
    for (int off = 32; off; off >>= 1) {
        s += __shfl_xor(s, off, 64);
        ss += __shfl_xor(ss, off, 64);
    }
    float mu = s * (1.f / 128.f);
    float var = ss * (1.f / 128.f) - mu * mu;
    float rs = rsqrtf(var + 1e-5f);
    float2 gg = *(const float2*)(g + lane * 2);
    float2 bb = *(const float2*)(b + lane * 2);
    float y0 = fmaxf((vx - mu) * rs * gg.x + bb.x, 0.f);
    float y1 = fmaxf((vy - mu) * rs * gg.y + bb.y, 0.f);
    *(float2*)(out + (size_t)wave * 128 + lane * 2) = make_float2(y0, y1);
}

// ---------------- fused pool0 + xc0 partials: 256 blocks x 32 rows ----------------
__global__ __launch_bounds__(256) void pool0_xc0(const float* __restrict__ latent,
                                                 const float* __restrict__ pW,
                                                 const float* __restrict__ pb,
                                                 const float* __restrict__ gum,
                                                 int* __restrict__ c0,
                                                 float* __restrict__ partials) {
    __shared__ float Ws[10 * 128];
    __shared__ float bs[10];
    __shared__ float acc[1280];
    for (int i = threadIdx.x; i < 1280; i += 256) { Ws[i] = pW[i]; acc[i] = 0.f; }
    if (threadIdx.x < 10) bs[threadIdx.x] = pb[threadIdx.x];
    __syncthreads();
    int lane = threadIdx.x & 63;
    int sub = lane & 7;                                   // 16-dim slice owner
    int row = blockIdx.x * 32 + (threadIdx.x >> 6) * 8 + (lane >> 3);

    const float4* lp = (const float4*)(latent + (size_t)row * 128 + sub * 16);
    float4 x0 = lp[0], x1 = lp[1], x2 = lp[2], x3 = lp[3];
    float2 gj[5];
    #pragma unroll
    for (int j = 0; j < 5; ++j) gj[j] = *(const float2*)(gum + (size_t)row * 10 + j * 2);

    float p[10];
    #pragma unroll
    for (int k = 0; k < 10; ++k) {
        const float4* wk = (const float4*)(Ws + k * 128 + sub * 16);
        float4 w0 = wk[0], w1 = wk[1], w2 = wk[2], w3 = wk[3];
        float a = x0.x * w0.x + x0.y * w0.y + x0.z * w0.z + x0.w * w0.w;
        a += x1.x * w1.x + x1.y * w1.y + x1.z * w1.z + x1.w * w1.w;
        a += x2.x * w2.x + x2.y * w2.y + x2.z * w2.z + x2.w * w2.w;
        a += x3.x * w3.x + x3.y * w3.y + x3.z * w3.z + x3.w * w3.w;
        p[k] = a;
    }
    #pragma unroll
    for (int off = 1; off < 8; off <<= 1) {
        #pragma unroll
        for (int k = 0; k < 10; ++k) p[k] += __shfl_xor(p[k], off, 64);
    }
    int best = 0;
    float bv = p[0] + bs[0] + gj[0].x;
    #pragma unroll
    for (int k = 1; k < 10; ++k) {
        float gk = (k & 1) ? gj[k >> 1].y : gj[k >> 1].x;
        float z = p[k] + bs[k] + gk;
        if (z > bv) { bv = z; best = k; }   // strict > : first max wins (jnp.argmax)
    }
    if (sub == 0) c0[row] = best;
    // all 8 lanes of the group agree on best; latent row is already in regs
    float* ap = acc + best * 128 + sub * 16;
    atomicAdd(ap + 0, x0.x);  atomicAdd(ap + 1, x0.y);
    atomicAdd(ap + 2, x0.z);  atomicAdd(ap + 3, x0.w);
    atomicAdd(ap + 4, x1.x);  atomicAdd(ap + 5, x1.y);
    atomicAdd(ap + 6, x1.z);  atomicAdd(ap + 7, x1.w);
    atomicAdd(ap + 8, x2.x);  atomicAdd(ap + 9, x2.y);
    atomicAdd(ap + 10, x2.z); atomicAdd(ap + 11, x2.w);
    atomicAdd(ap + 12, x3.x); atomicAdd(ap + 13, x3.y);
    atomicAdd(ap + 14, x3.z); atomicAdd(ap + 15, x3.w);
    __syncthreads();
    for (int i = threadIdx.x; i < 1280; i += 256)
        partials[(size_t)blockIdx.x * 1280 + i] = acc[i];
}

// ---------------- fused: blocks [0,256) A0 edge-pool; blocks [256,266) xc0 reduce ----------------
__global__ __launch_bounds__(256) void adj_xc0(const int* __restrict__ ei,
                                               const float* __restrict__ ew,
                                               const int* __restrict__ c0,
                                               float* __restrict__ A0,
                                               const float* __restrict__ partials,
                                               float* __restrict__ xc0, int E) {
    if (blockIdx.x < 256) {
        __shared__ float As[100];
        for (int i = threadIdx.x; i < 100; i += 256) As[i] = 0.f;
        __syncthreads();
        const int* src = ei;
        const int* dst = ei + E;
        for (int e = blockIdx.x * 256 + threadIdx.x; e < E; e += 256 * 256) {
            int a = c0[src[e]], b = c0[dst[e]];
            atomicAdd(&As[a * 10 + b], ew[e]);
        }
        __syncthreads();
        for (int i = threadIdx.x; i < 100; i += 256) atomicAdd(&A0[i], As[i]);
    } else {
        int k = blockIdx.x - 256;
        int d = threadIdx.x & 127;
        int half = threadIdx.x >> 7;
        int b0 = half * 128;
        float s0 = 0.f, s1 = 0.f, s2 = 0.f, s3 = 0.f;
        for (int b = b0; b < b0 + 128; b += 4) {
            s0 += partials[(size_t)(b    ) * 1280 + k * 128 + d];
            s1 += partials[(size_t)(b + 1) * 1280 + k * 128 + d];
            s2 += partials[(size_t)(b + 2) * 1280 + k * 128 + d];
            s3 += partials[(size_t)(b + 3) * 1280 + k * 128 + d];
        }
        __shared__ float sm[256];
        sm[threadIdx.x] = (s0 + s1) + (s2 + s3);
        __syncthreads();
        if (threadIdx.x < 128) xc0[k * 128 + d] = sm[threadIdx.x] + sm[threadIdx.x + 128];
    }
}

// ---------------- single-block: levels 0/1 coarse math -> tbl[10][16] ----------------
__global__ __launch_bounds__(256) void small_kernel(const float* __restrict__ xc0,
                                                    const float* __restrict__ A0,
                                                    const float* __restrict__ gum1,
                                                    const float* __restrict__ p1W,
                                                    const float* __restrict__ p1b,
                                                    const float* __restrict__ e0W,
                                                    const float* __restrict__ e0b,
                                                    const float* __restrict__ e1W,
                                                    const float* __restrict__ e1b,
                                                    const float* __restrict__ fcW,
                                                    const float* __restrict__ fcb,
                                                    float* __restrict__ tbl) {
    __shared__ float xc0n[10 * 128];
    __shared__ float adj0[100];
    __shared__ float m0[10 * 128];
    __shared__ float l1[10 * 128];
    __shared__ float xc1n[5 * 128];
    __shared__ float l2[5 * 128];
    __shared__ float A1[25];
    __shared__ int c1[10];
    __shared__ float red[4];

    int tid = threadIdx.x;
    int wid = tid >> 6, lane = tid & 63;

    // xc0 row-normalize
    for (int r = wid; r < 10; r += 4) {
        float2 v = *(const float2*)(xc0 + r * 128 + lane * 2);
        float ss = v.x * v.x + v.y * v.y;
        for (int off = 32; off; off >>= 1) ss += __shfl_xor(ss, off, 64);
        float sc = 1.f / fmaxf(sqrtf(ss), 1e-12f);
        xc0n[r * 128 + lane * 2] = v.x * sc;
        xc0n[r * 128 + lane * 2 + 1] = v.y * sc;
    }
    __syncthreads();
    // adj0 = A0 / (sum(A0) + 100*1e-8)
    if (tid == 0) {
        float s = 0.f;
        for (int i = 0; i < 100; ++i) s += A0[i];
        red[0] = s + 1e-6f;
    }
    __syncthreads();
    if (tid < 100) adj0[tid] = A0[tid] / red[0];
    __syncthreads();
    // m0 = adj0 @ xc0n
    for (int idx = tid; idx < 1280; idx += 256) {
        int r = idx >> 7, d = idx & 127;
        float acc = 0.f;
        #pragma unroll
        for (int a = 0; a < 10; ++a) acc += adj0[r * 10 + a] * xc0n[a * 128 + d];
        m0[idx] = acc;
    }
    __syncthreads();
    // l1 = relu(m0 @ e0W^T + e0b)
    for (int idx = tid; idx < 1280; idx += 256) {
        int r = idx >> 7, d = idx & 127;
        float acc = e0b[d];
        const float* wrow = e0W + d * 128;
        for (int k = 0; k < 128; ++k) acc += m0[r * 128 + k] * wrow[k];
        l1[idx] = fmaxf(acc, 0.f);
    }
    __syncthreads();
    // logits1 + gumbel1 argmax -> c1
    if (tid < 10) {
        int best = 0;
        float bv = -1e30f;
        for (int j = 0; j < 5; ++j) {
            float acc = p1b[j] + gum1[tid * 5 + j];
            const float* wrow = p1W + j * 128;
            for (int k = 0; k < 128; ++k) acc += l1[tid * 128 + k] * wrow[k];
            if (acc > bv) { bv = acc; best = j; }
        }
        c1[tid] = best;
    }
    __syncthreads();
    // xc1 = segsum(l1 by c1)
    for (int idx = tid; idx < 640; idx += 256) {
        int m = idx >> 7, d = idx & 127;
        float acc = 0.f;
        #pragma unroll
        for (int k = 0; k < 10; ++k)
            if (c1[k] == m) acc += l1[k * 128 + d];
        xc1n[idx] = acc;
    }
    __syncthreads();
    // normalize rows of xc1
    for (int r = wid; r < 5; r += 4) {
        float2 v = *(const float2*)(xc1n + r * 128 + lane * 2);
        float ss = v.x * v.x + v.y * v.y;
        for (int off = 32; off; off >>= 1) ss += __shfl_xor(ss, off, 64);
        float sc = 1.f / fmaxf(sqrtf(ss), 1e-12f);
        xc1n[r * 128 + lane * 2] = v.x * sc;
        xc1n[r * 128 + lane * 2 + 1] = v.y * sc;
    }
    __syncthreads();
    // A1[m,n] = sum_{a,b} adj0[a,b][c1[a]=m][c1[b]=n]
    if (tid < 25) {
        int m = tid / 5, n = tid % 5;
        float acc = 0.f;
        for (int a = 0; a < 10; ++a)
            for (int b = 0; b < 10; ++b)
                if (c1[a] == m && c1[b] == n) acc += adj0[a * 10 + b];
        A1[tid] = acc;
    }
    __syncthreads();
    if (tid == 0) {
        float s = 0.f;
        for (int i = 0; i < 25; ++i) s += A1[i];
        red[1] = s + 25e-8f;
    }
    __syncthreads();
    float den1 = red[1];
    // m1 = (A1/den1) @ xc1n   (reuse m0)
    for (int idx = tid; idx < 640; idx += 256) {
        int r = idx >> 7, d = idx & 127;
        float acc = 0.f;
        #pragma unroll
        for (int a = 0; a < 5; ++a) acc += A1[r * 5 + a] * xc1n[a * 128 + d];
        m0[idx] = acc / den1;
    }
    __syncthreads();
    // l2 = relu(m1 @ e1W^T + e1b)
    for (int idx = tid; idx < 640; idx += 256) {
        int r = idx >> 7, d = idx & 127;
        float acc = e1b[d];
        const float* wrow = e1W + d * 128;
        for (int k = 0; k < 128; ++k) acc += m0[r * 128 + k] * wrow[k];
        l2[idx] = fmaxf(acc, 0.f);
    }
    __syncthreads();
    // tbl[k][o] = fcb[o] + l1[k]·fcW[o,128:256] + l2[c1[k]]·fcW[o,256:384]
    for (int idx = tid; idx < 160; idx += 256) {
        int k = idx >> 4, o = idx & 15;
        float acc = fcb[o];
        const float* fB = fcW + o * 384 + 128;
        const float* fC = fcW + o * 384 + 256;
        const float* a1 = l1 + k * 128;
        const float* a2 = l2 + c1[k] * 128;
        for (int d = 0; d < 128; ++d) acc += a1[d] * fB[d] + a2[d] * fC[d];
        tbl[idx] = acc;
    }
}

// ---------------- out[i] = latent[i] @ fcA^T + tbl[c0[i]], 8-lane groups ----------------
__global__ __launch_bounds__(256) void out_kernel(const float* __restrict__ latent,
                                                  const int* __restrict__ c0,
                                                  const float* __restrict__ tbl,
                                                  const float* __restrict__ fcW,
                                                  float* __restrict__ out) {
    __shared__ float fA[16 * 128];
    __shared__ float ts[160];
    for (int i = threadIdx.x; i < 2048; i += 256) {
        int o = i >> 7, d = i & 127;
        fA[i] = fcW[o * 384 + d];
    }
    for (int i = threadIdx.x; i < 160; i += 256) ts[i] = tbl[i];
    __syncthreads();
    int lane = threadIdx.x & 63;
    int sub = lane & 7;
    int row = blockIdx.x * 32 + (threadIdx.x >> 6) * 8 + (lane >> 3);
    const float4* lp = (const float4*)(latent + (size_t)row * 128 + sub * 16);
    float4 x0 = lp[0], x1 = lp[1], x2 = lp[2], x3 = lp[3];
    float p[16];
    #pragma unroll
    for (int o = 0; o < 16; ++o) {
        const float4* fo = (const float4*)(fA + o * 128 + sub * 16);
        float4 w0 = fo[0], w1 = fo[1], w2 = fo[2], w3 = fo[3];
        float a = x0.x * w0.x + x0.y * w0.y + x0.z * w0.z + x0.w * w0.w;
        a += x1.x * w1.x + x1.y * w1.y + x1.z * w1.z + x1.w * w1.w;
        a += x2.x * w2.x + x2.y * w2.y + x2.z * w2.z + x2.w * w2.w;
        a += x3.x * w3.x + x3.y * w3.y + x3.z * w3.z + x3.w * w3.w;
        p[o] = a;
    }
    #pragma unroll
    for (int off = 1; off < 8; off <<= 1) {
        #pragma unroll
        for (int o = 0; o < 16; ++o) p[o] += __shfl_xor(p[o], off, 64);
    }
    int c = c0[row];
    float2 r = make_float2(p[2 * sub] + ts[c * 16 + 2 * sub],
                           p[2 * sub + 1] + ts[c * 16 + 2 * sub + 1]);
    *(float2*)(out + (size_t)row * 16 + 2 * sub) = r;
}

extern "C" void kernel_launch(void* const* d_in, const int* in_sizes, int n_in,
                              void* d_out, int out_size, void* d_ws, size_t ws_size,
                              hipStream_t stream) {
    const float* x    = (const float*)d_in[0];
    const int*   ei   = (const int*)d_in[1];
    const float* ew   = (const float*)d_in[2];
    const float* g0   = (const float*)d_in[3];
    const float* g1   = (const float*)d_in[4];
    const float* Wg1  = (const float*)d_in[5];
    const float* bg1  = (const float*)d_in[6];
    const float* ln1g = (const float*)d_in[7];
    const float* ln1b = (const float*)d_in[8];
    const float* Wg2  = (const float*)d_in[9];
    const float* bg2  = (const float*)d_in[10];
    const float* ln2g = (const float*)d_in[11];
    const float* ln2b = (const float*)d_in[12];
    const float* p0W  = (const float*)d_in[13];
    const float* p0b  = (const float*)d_in[14];
    const float* p1W  = (const float*)d_in[15];
    const float* p1b  = (const float*)d_in[16];
    const float* e0W  = (const float*)d_in[17];
    const float* e0b  = (const float*)d_in[18];
    const float* e1W  = (const float*)d_in[19];
    const float* e1b  = (const float*)d_in[20];
    const float* fcW  = (const float*)d_in[21];
    const float* fcb  = (const float*)d_in[22];
    float* out = (float*)d_out;

    float* ws   = (float*)d_ws;
    float* bufA = ws;                                        // N*128 f
    float* bufB = bufA + (size_t)N_NODES * 128;              // N*128 f
    int*   c0   = (int*)(bufB + (size_t)N_NODES * 128);      // N int
    float* xc0  = (float*)(c0 + N_NODES);                    // 1280 f
    float* tbl  = xc0 + 1280;                                // 160 f
    int*   deg  = (int*)(tbl + 160);                         // 8192 int   <- memset start
    float* A0   = (float*)(deg + N_NODES);                   // 100 f      <- contiguous with deg
    int*   row_start = (int*)(A0 + 100);                     // 8194 int (padded for alignment)
    int*   cursor    = row_start + N_NODES + 2;              // 8192 int
    int2*  esort     = (int2*)(cursor + N_NODES);            // E int2 (8-B aligned)
    float* partials  = bufA;   // 256*1280 f = 1.31 MB, reuses bufA (free after 2nd agg)

    // zero deg + A0 in ONE fill (contiguous)
    hipMemsetAsync(deg, 0, (N_NODES + 100) * sizeof(int), stream);

    // layer 1 gemm (agg commutes: agg(x) @ W^T == agg(x @ W^T)) fused with dst-histogram
    gemm1_hist<<<N_NODES / 8 + 64, 128, 0, stream>>>(x, Wg1, bufA, ei, deg);
    scan_kernel<<<1, 256, 0, stream>>>(deg, row_start, cursor);
    scatter_kernel<<<N_EDGES / 256, 256, 0, stream>>>(ei, ew, cursor, esort, N_EDGES);
    agg_ln_csr<<<N_NODES / 4, 256, 0, stream>>>(row_start, esort, bufA, bufB,
                                                bg1, ln1g, ln1b);

    // layer 2
    gemm_rows<NHID><<<N_NODES / 8, 128, 0, stream>>>(bufB, Wg2, bufA);
    agg_ln_csr<<<N_NODES / 4, 256, 0, stream>>>(row_start, esort, bufA, bufB,
                                                bg2, ln2g, ln2b);
    // bufB = latent [N,128]; bufA now free -> partials

    // level-0 pooling: c0 + LDS xc0 partials in one kernel
    pool0_xc0<<<256, 256, 0, stream>>>(bufB, p0W, p0b, g0, c0, partials);
    // A0 edge-pool + xc0 reduction fused (independent block ranges)
    adj_xc0<<<266, 256, 0, stream>>>(ei, ew, c0, A0, partials, xc0, N_EDGES);

    // coarse levels -> tbl
    small_kernel<<<1, 256, 0, stream>>>(xc0, A0, g1, p1W, p1b, e0W, e0b, e1W, e1b,
                                        fcW, fcb, tbl);

    // final: out = latent @ fcA^T + tbl[c0]
    out_kernel<<<256, 256, 0, stream>>>(bufB, c0, tbl, fcW, out);
}